// Round 2
// baseline (150.405 us; speedup 1.0000x reference)
//
#include <hip/hip_runtime.h>
#include <hip/hip_bf16.h>
#include <math.h>

// Problem constants
#define BB 2
#define MM 9          // 1 query + 8 supports
#define MS 8
#define DD 256
#define HW 2304       // 48*48
#define NCLS 4
#define OUTR 224

typedef float floatx4 __attribute__((ext_vector_type(4)));
typedef __bf16 bf16x8 __attribute__((ext_vector_type(8)));
typedef unsigned short ushortx8 __attribute__((ext_vector_type(8)));

// order-preserving float <-> uint encode for atomicMax
__device__ __forceinline__ unsigned enc_f(float f) {
    unsigned u = __float_as_uint(f);
    return (u & 0x80000000u) ? ~u : (u | 0x80000000u);
}
__device__ __forceinline__ float dec_f(unsigned k) {
    unsigned u = (k & 0x80000000u) ? (k & 0x7FFFFFFFu) : ~k;
    return __uint_as_float(u);
}

// ---------------- Kernel 1: 32-pix tiles, 4 blocks/CU, float4 loads ---------------------------
// in : emb[bm][d][pix] fp32 ; out: normed[bm][pix][d] bf16. Also zero-inits enc_logits.
__global__ __launch_bounds__(256) void knorm(const float* __restrict__ emb,
                                             __hip_bfloat16* __restrict__ outp,
                                             unsigned* __restrict__ enc_logits) {
    __shared__ float tile[256][33];   // [d][pix], +1 pad
    __shared__ float psum[8][32];
    __shared__ float sscale[32];
    const int bm   = blockIdx.y;
    const int pix0 = blockIdx.x * 32;
    const int tid  = threadIdx.x;

    // fused init of encoded logits (BB*NCLS*HW = 18432 entries; key 0 < any enc(finite))
    int flat = (blockIdx.y * gridDim.x + blockIdx.x) * 256 + tid;
    if (flat < BB * NCLS * HW) enc_logits[flat] = 0u;

    const float* src = emb + (size_t)bm * DD * HW + pix0;
    {
        const int dr = tid >> 3;          // 0..31
        const int p4 = (tid & 7) * 4;     // 0..28
#pragma unroll
        for (int r = 0; r < 8; ++r) {
            int d = r * 32 + dr;
            floatx4 v = *(const floatx4*)(src + (size_t)d * HW + p4);
            float* t = &tile[d][p4];
            t[0] = v[0]; t[1] = v[1]; t[2] = v[2]; t[3] = v[3];
        }
    }
    __syncthreads();
    {
        const int pc = tid & 31;
        const int dr = tid >> 5;          // 0..7
        float ss = 0.f;
#pragma unroll
        for (int s = 0; s < 32; ++s) {
            float v = tile[dr * 32 + s][pc];
            ss += v * v;
        }
        psum[dr][pc] = ss;
    }
    __syncthreads();
    if (tid < 32) {
        float t = 0.f;
#pragma unroll
        for (int c = 0; c < 8; ++c) t += psum[c][tid];
        sscale[tid] = 1.0f / fmaxf(sqrtf(t), 1e-12f);
    }
    __syncthreads();
    __hip_bfloat16* dst = outp + (size_t)bm * HW * DD + (size_t)pix0 * DD;
#pragma unroll
    for (int r = 0; r < 32; ++r) {
        float v = tile[tid][r] * sscale[r];
        dst[(size_t)r * DD + tid] = __float2bfloat16(v);
    }
}

// ---------------- Kernel 2: bf16 MFMA GEMM + fused mask + running per-class max ----------------
__device__ __forceinline__ void gld16(const unsigned short* g, unsigned short* l) {
    __builtin_amdgcn_global_load_lds((__attribute__((address_space(1))) void*)g,
                                     (__attribute__((address_space(3))) void*)l, 16, 0, 0);
}

#define NKT 3                 // column tiles per block
#define BK 64
#define REDSTRIDE 132
// LDS: 2 bufs x (A 16KB + B 16KB) = 65536 B; epilogue red[64][132] f32 = 33792 B (union)
#define SMEM_BYTES 65536

// grid: (48 = m*6 + cg, 18 = row tile, 2 = b); block 256 (4 waves), 2 blocks/CU
__global__ __launch_bounds__(256, 2) void kgemm(const unsigned short* __restrict__ normed,
                                                const float* __restrict__ pm,
                                                unsigned* __restrict__ enc_logits) {
    __shared__ __attribute__((aligned(16))) unsigned char smem[SMEM_BYTES];
    unsigned short* const S = (unsigned short*)smem;   // buf c: A at c*16384, B at c*16384+8192 (shorts)
    float* red = (float*)smem;                         // union (staging dead in epilogue)

    const int gx = blockIdx.x;       // 0..47
    const int rt = blockIdx.y;       // 0..17
    const int b  = blockIdx.z;
    const int m  = gx / 6;           // support index 0..7
    const int cg = gx % 6;           // column-tile group
    const int kt0 = cg * NKT;

    const int tid  = threadIdx.x;
    const int lane = tid & 63;
    const int wave = tid >> 6;
    const int wr = wave >> 1, wc = wave & 1;
    const int lrow = lane & 15;
    const int quad = lane >> 4;      // 0..3

    const unsigned short* A  = normed + (size_t)(b * MM) * (HW * DD) + (size_t)(rt * 128) * DD;
    const unsigned short* Bp = normed + (size_t)(b * MM + 1 + m) * (HW * DD);
    const float* pmB = pm + (size_t)(b * MS + m) * NCLS * HW;

    // staging: instr g = wave*4+q covers rows g*8..g*8+7. Lane l: row g*8+(l>>3), phys
    // chunk l&7 holds logical chunk (l&7)^(row&7)  ->  conflict-free b128 reads.
    const int srow = lane >> 3;                        // 0..7 (row within 8-row group)
    const int sc   = ((lane & 7) ^ srow) * 8;          // logical chunk * 8 elems
    const unsigned short* gA = A  + (size_t)(wave * 32 + srow) * DD + sc;
    const unsigned short* gB = Bp + (size_t)(wave * 32 + srow) * DD + sc;

    // read-side phys chunk per kk (same for A and B: row&7 == lrow&7)
    const int pc0 = ((0 * 4 + quad) ^ (lrow & 7)) * 8;
    const int pc1 = ((1 * 4 + quad) ^ (lrow & 7)) * 8;

    floatx4 zero = {0.f, 0.f, 0.f, 0.f};
    floatx4 acc[4][4];
#pragma unroll
    for (int i = 0; i < 4; ++i)
#pragma unroll
        for (int j = 0; j < 4; ++j) acc[i][j] = zero;

    float omax[4][4][4];
#pragma unroll
    for (int n = 0; n < 4; ++n)
#pragma unroll
        for (int i = 0; i < 4; ++i)
#pragma unroll
            for (int r = 0; r < 4; ++r) omax[n][i][r] = -INFINITY;

#define STAGE(bufN, ktS, k0S) do {                                             \
        unsigned short* dA_ = S + (bufN) * 16384 + wave * 4 * 512;             \
        unsigned short* dB_ = dA_ + 8192;                                      \
        const unsigned short* sA_ = gA + (k0S);                                \
        const unsigned short* sB_ = gB + (size_t)(ktS) * 128 * DD + (k0S);     \
        _Pragma("unroll")                                                      \
        for (int q_ = 0; q_ < 4; ++q_) {                                       \
            gld16(sA_ + (size_t)(q_ * 8) * DD, dA_ + q_ * 512);                \
            gld16(sB_ + (size_t)(q_ * 8) * DD, dB_ + q_ * 512);                \
        }                                                                      \
    } while (0)

    // prologue: stage (kt0, k0=0) into buf 0
    STAGE(0, kt0, 0);
    __syncthreads();

    for (int ktl = 0; ktl < NKT; ++ktl) {
        const int kt = kt0 + ktl;
        // mask loads for this kt (latency hides under the 4 compute steps)
        float mp1[4], mp2[4], mp3[4];
#pragma unroll
        for (int j = 0; j < 4; ++j) {
            int kp = kt * 128 + wc * 64 + j * 16 + lrow;
            mp1[j] = pmB[HW + kp];
            mp2[j] = pmB[2 * HW + kp];
            mp3[j] = pmB[3 * HW + kp];
        }
#pragma unroll
        for (int k0i = 0; k0i < 4; ++k0i) {
            const int cur = k0i & 1;
            // stage next step into the other buffer (skip after the very last step)
            if (!(ktl == NKT - 1 && k0i == 3)) {
                if (k0i == 3) STAGE(cur ^ 1, kt + 1, 0);
                else          STAGE(cur ^ 1, kt, (k0i + 1) * BK);
            }
            const unsigned short* Ac = S + cur * 16384;
            const unsigned short* Bc = Ac + 8192;
#pragma unroll
            for (int kk = 0; kk < 2; ++kk) {
                const int pc = kk ? pc1 : pc0;
                bf16x8 af[4], bfr[4];
#pragma unroll
                for (int i = 0; i < 4; ++i) {
                    int ar = wr * 64 + i * 16 + lrow;
                    int br = wc * 64 + i * 16 + lrow;
                    af[i]  = __builtin_bit_cast(bf16x8, *(const ushortx8*)(Ac + ar * 64 + pc));
                    bfr[i] = __builtin_bit_cast(bf16x8, *(const ushortx8*)(Bc + br * 64 + pc));
                }
#pragma unroll
                for (int i = 0; i < 4; ++i)
#pragma unroll
                    for (int j = 0; j < 4; ++j)
                        acc[i][j] = __builtin_amdgcn_mfma_f32_16x16x32_bf16(af[i], bfr[j], acc[i][j], 0, 0, 0);
            }
            if (k0i == 3) {
                // fold this tile's masked per-class max into running omax, reset acc
                int mj[4];
#pragma unroll
                for (int j = 0; j < 4; ++j)
                    mj[j] = ((mp1[j] + mp2[j] + mp3[j] == 0.0f) ? 1 : 0) | (mp1[j] != 0.0f ? 2 : 0) |
                            (mp2[j] != 0.0f ? 4 : 0) | (mp3[j] != 0.0f ? 8 : 0);
#pragma unroll
                for (int n = 0; n < 4; ++n) {
                    bool b0 = (mj[0] >> n) & 1, b1 = (mj[1] >> n) & 1;
                    bool b2 = (mj[2] >> n) & 1, b3 = (mj[3] >> n) & 1;
#pragma unroll
                    for (int i = 0; i < 4; ++i)
#pragma unroll
                        for (int r = 0; r < 4; ++r) {
                            float t0 = b0 ? acc[i][0][r] : -INFINITY;
                            float t1 = b1 ? acc[i][1][r] : -INFINITY;
                            float t2 = b2 ? acc[i][2][r] : -INFINITY;
                            float t3 = b3 ? acc[i][3][r] : -INFINITY;
                            omax[n][i][r] = fmaxf(omax[n][i][r],
                                                  fmaxf(fmaxf(t0, t1), fmaxf(t2, t3)));
                        }
                }
#pragma unroll
                for (int i = 0; i < 4; ++i)
#pragma unroll
                    for (int j = 0; j < 4; ++j) acc[i][j] = zero;
            }
            __syncthreads();
        }
    }
#undef STAGE

    // ---- epilogue (once per block): LDS transpose-reduce of omax, then atomicMax ----
    const int col32 = wc * 16 + lrow;
#pragma unroll
    for (int p = 0; p < 2; ++p) {
        if (p) __syncthreads();
#pragma unroll
        for (int nn = 0; nn < 2; ++nn) {
            int n = p * 2 + nn;
#pragma unroll
            for (int i = 0; i < 4; ++i) {
                floatx4 o;
#pragma unroll
                for (int r = 0; r < 4; ++r) o[r] = omax[n][i][r];
                int rowbase = wr * 64 + i * 16 + quad * 4;
                *(floatx4*)(red + ((size_t)(nn * 32 + col32)) * REDSTRIDE + rowbase) = o;
            }
        }
        __syncthreads();
        {
            int nn  = tid >> 7;
            int row = tid & 127;
            float v = -INFINITY;
#pragma unroll
            for (int c = 0; c < 32; ++c)
                v = fmaxf(v, red[((size_t)(nn * 32 + c)) * REDSTRIDE + row]);
            int n = p * 2 + nn;
            atomicMax(enc_logits + ((size_t)b * NCLS + n) * HW + rt * 128 + row, enc_f(v));
        }
    }
}

// ---------------- Kernel 3: bilinear 48 -> 224 (decode) + -inf fix on ch 0 ---------------------
__global__ __launch_bounds__(256) void kresize(const unsigned* __restrict__ enc_logits,
                                               float* __restrict__ out) {
    int idx = blockIdx.x * 256 + threadIdx.x;   // BB*NCLS*224*224
    if (idx >= BB * NCLS * OUTR * OUTR) return;
    int ox = idx % OUTR;
    int oy = (idx / OUTR) % OUTR;
    int bn = idx / (OUTR * OUTR);
    const unsigned* src = enc_logits + (size_t)bn * HW;
    const float inv = 48.0f / 224.0f;
    float sx = (ox + 0.5f) * inv - 0.5f;
    float sy = (oy + 0.5f) * inv - 0.5f;
    int x0 = (int)floorf(sx); float fx = sx - x0;
    int y0 = (int)floorf(sy); float fy = sy - y0;
    int x0c = min(max(x0, 0), 47), x1c = min(max(x0 + 1, 0), 47);
    int y0c = min(max(y0, 0), 47), y1c = min(max(y0 + 1, 0), 47);
    float v00 = dec_f(src[y0c * 48 + x0c]), v01 = dec_f(src[y0c * 48 + x1c]);
    float v10 = dec_f(src[y1c * 48 + x0c]), v11 = dec_f(src[y1c * 48 + x1c]);
    float v = (1.f - fy) * ((1.f - fx) * v00 + fx * v01) + fy * ((1.f - fx) * v10 + fx * v11);
    if ((bn & 3) == 0 && v == -INFINITY) v = 0.f;
    out[idx] = v;
}

// ---------------- launch ------------------------------------------------------------------------
extern "C" void kernel_launch(void* const* d_in, const int* in_sizes, int n_in,
                              void* d_out, int out_size, void* d_ws, size_t ws_size,
                              hipStream_t stream) {
    const float* emb = (const float*)d_in[0];   // (2,9,256,48,48) fp32
    const float* pm  = (const float*)d_in[1];   // (2,8,4,48,48) fp32
    float* out = (float*)d_out;                 // (2,4,224,224) fp32

    char* ws = (char*)d_ws;
    const size_t normed_bytes = (size_t)BB * MM * HW * DD * 2;   // 21,233,664
    __hip_bfloat16* normed = (__hip_bfloat16*)(ws);
    unsigned*       enc    = (unsigned*)(ws + normed_bytes);     // BB*NCLS*HW uints

    knorm<<<dim3(HW / 32, BB * MM), 256, 0, stream>>>(emb, normed, enc);
    kgemm<<<dim3(48, 18, BB), 256, 0, stream>>>((const unsigned short*)normed, pm, enc);
    kresize<<<(BB * NCLS * OUTR * OUTR + 255) / 256, 256, 0, stream>>>(enc, out);
}